// Round 2
// baseline (2421.709 us; speedup 1.0000x reference)
//
#include <hip/hip_runtime.h>
#include <hip/hip_bf16.h>

typedef __attribute__((ext_vector_type(8))) short short8;
typedef __attribute__((ext_vector_type(4))) float f32x4;

#define R_TOTAL 131072   // B*S
#define KDIM 2048        // ENC
#define NDIM 1024        // ATT
#define SDIM 2048
#define BDIM 64
#define MASK_FILL -1000000009.0f

__device__ __forceinline__ unsigned short f2bf(float f) {
    unsigned int u = __builtin_bit_cast(unsigned int, f);
    unsigned int r = u + 0x7FFFu + ((u >> 16) & 1u);   // RNE
    return (unsigned short)(r >> 16);
}

__device__ __forceinline__ void gload_lds16(const void* g, void* l) {
    __builtin_amdgcn_global_load_lds(
        (const __attribute__((address_space(1))) unsigned int*)g,
        (__attribute__((address_space(3))) unsigned int*)l, 16, 0, 0);
}

// ---------------- K0: fp32 -> bf16 convert (grid-stride, 8 el/thread) ----------------
__global__ void cvt_bf16_kernel(const float* __restrict__ in,
                                unsigned short* __restrict__ out, size_t n) {
    size_t i0 = ((size_t)blockIdx.x * 256 + threadIdx.x) * 8;
    size_t stride = (size_t)gridDim.x * 256 * 8;
    for (size_t i = i0; i < n; i += stride) {
        float4 a = *reinterpret_cast<const float4*>(in + i);
        float4 b = *reinterpret_cast<const float4*>(in + i + 4);
        short8 o;
        o[0] = (short)f2bf(a.x); o[1] = (short)f2bf(a.y);
        o[2] = (short)f2bf(a.z); o[3] = (short)f2bf(a.w);
        o[4] = (short)f2bf(b.x); o[5] = (short)f2bf(b.y);
        o[6] = (short)f2bf(b.z); o[7] = (short)f2bf(b.w);
        *reinterpret_cast<short8*>(out + i) = o;
    }
}

// ---------------- K1: dec_proj[b][a] = sum_h dec[b][h] * W[a][h] ----------------
__global__ void decproj_kernel(const float* __restrict__ dec,
                               const float* __restrict__ W,
                               float* __restrict__ dp) {
    int a0 = blockIdx.x << 6;           // 16 blocks of 64 a's
    int tid = threadIdx.x;
    __shared__ float sD[64][129];
    __shared__ float sW[64][129];
    int al = tid & 63, bg = tid >> 6;   // bg 0..3 -> 16 b's each
    float acc[16];
#pragma unroll
    for (int i = 0; i < 16; ++i) acc[i] = 0.f;

    for (int h0 = 0; h0 < 1024; h0 += 128) {
        __syncthreads();
#pragma unroll
        for (int i = 0; i < 8; ++i) {
            int f = tid + (i << 8);
            int row = f >> 5, c = (f & 31) << 2;
            float4 v = *reinterpret_cast<const float4*>(dec + (size_t)row * 1024 + h0 + c);
            sD[row][c] = v.x; sD[row][c + 1] = v.y; sD[row][c + 2] = v.z; sD[row][c + 3] = v.w;
            float4 w = *reinterpret_cast<const float4*>(W + (size_t)(a0 + row) * 1024 + h0 + c);
            sW[row][c] = w.x; sW[row][c + 1] = w.y; sW[row][c + 2] = w.z; sW[row][c + 3] = w.w;
        }
        __syncthreads();
        for (int h = 0; h < 128; ++h) {
            float w = sW[al][h];
#pragma unroll
            for (int i = 0; i < 16; ++i) acc[i] += w * sD[(bg << 4) + i][h];
        }
    }
#pragma unroll
    for (int i = 0; i < 16; ++i)
        dp[(size_t)((bg << 4) + i) * 1024 + a0 + al] = acc[i];
}

// ======= K2 (fast path): m97-structure GEMM on bf16 + fused tanh/v-dot =======
// flat grid 8192; decode: xcd group c = h&7 owns rowb in [c*128, c*128+128);
// slot = h>>3: rowb = c*128 + (slot>>3), colb = slot&7  (8 colb sharing a rowb
// run consecutively on one XCD -> A-panel L2 reuse).
__global__ __launch_bounds__(256, 2) void eij_gl_kernel(
        const unsigned short* __restrict__ enc16,
        const unsigned short* __restrict__ ua16,
        const float* __restrict__ decp, const float* __restrict__ va,
        float* __restrict__ Epart) {
    const int h = blockIdx.x;
    const int c = h & 7, slot = h >> 3;
    const int rowb = c * 128 + (slot >> 3);
    const int colb = slot & 7;
    const int tid  = threadIdx.x;
    const int lane = tid & 63, wid = tid >> 6;
    const int wr = wid >> 1, wc = wid & 1;         // 2x2 wave grid, 64x64 per wave
    const int b  = rowb >> 4;

    __shared__ unsigned short sA[128 * 64];
    __shared__ unsigned short sB[128 * 64];
    __shared__ float sEw[2][128];

    // per-lane global sources for global_load_lds (16 B/lane), pre-swizzled:
    // logical LDS image: row-major [128][64] bf16, swizzled by el_idx ^= (row&7)<<3.
    // chunk j covers rows (wid*4+j)*8 .. +8; lane covers row +=(lane>>3),
    // granule g = lane&7; row&7 == lane>>3  =>  src granule = (lane&7)^(lane>>3).
    const unsigned short* aSrc[4];
    const unsigned short* bSrc[4];
    unsigned short* aDst[4];
    unsigned short* bDst[4];
#pragma unroll
    for (int j = 0; j < 4; ++j) {
        int chunk = (wid << 2) + j;
        int row = (chunk << 3) + (lane >> 3);
        int gsw = ((lane & 7) ^ (lane >> 3)) << 3;   // element offset within row
        aSrc[j] = enc16 + (size_t)(rowb * 128 + row) * KDIM + gsw;
        bSrc[j] = ua16 + (size_t)(colb * 128 + row) * KDIM + gsw;
        aDst[j] = &sA[chunk << 9];
        bDst[j] = &sB[chunk << 9];
    }

    f32x4 acc[4][4];
#pragma unroll
    for (int i = 0; i < 4; ++i)
#pragma unroll
        for (int j = 0; j < 4; ++j) acc[i][j] = (f32x4){0.f, 0.f, 0.f, 0.f};

    for (int k0 = 0; k0 < KDIM; k0 += 64) {
        __syncthreads();   // prior tile's ds_reads done
#pragma unroll
        for (int j = 0; j < 4; ++j) {
            gload_lds16(aSrc[j] + k0, aDst[j]);
            gload_lds16(bSrc[j] + k0, bDst[j]);
        }
        __syncthreads();   // compiler drains vmcnt(0) before barrier -> tile ready
#pragma unroll
        for (int kk = 0; kk < 64; kk += 32) {
            const int kb = kk + ((lane >> 4) << 3);
            const int rsw = (lane & 7) << 3;       // read-side swizzle: row&7 == lane&7
            short8 af[4], bf_[4];
#pragma unroll
            for (int fr = 0; fr < 4; ++fr) {
                int row = (wr << 6) + (fr << 4) + (lane & 15);
                int idx = (row * 64 + kb) ^ rsw;
                af[fr] = *reinterpret_cast<const short8*>(&sA[idx]);
            }
#pragma unroll
            for (int fc = 0; fc < 4; ++fc) {
                int row = (wc << 6) + (fc << 4) + (lane & 15);
                int idx = (row * 64 + kb) ^ rsw;
                bf_[fc] = *reinterpret_cast<const short8*>(&sB[idx]);
            }
#pragma unroll
            for (int fr = 0; fr < 4; ++fr)
#pragma unroll
                for (int fc = 0; fc < 4; ++fc)
                    acc[fr][fc] = __builtin_amdgcn_mfma_f32_16x16x32_bf16(
                        af[fr], bf_[fc], acc[fr][fc], 0, 0, 0);
        }
    }

    // epilogue: E_partial[row] = sum_cols v[a] * tanh(acc + dec_proj[b][a])
    float dv[4], vv[4];
#pragma unroll
    for (int fc = 0; fc < 4; ++fc) {
        int colg = (colb << 7) + (wc << 6) + (fc << 4) + (lane & 15);
        dv[fc] = decp[(size_t)b * 1024 + colg];
        vv[fc] = va[colg];
    }
#pragma unroll
    for (int fr = 0; fr < 4; ++fr) {
#pragma unroll
        for (int i = 0; i < 4; ++i) {
            float s = 0.f;
#pragma unroll
            for (int fc = 0; fc < 4; ++fc)
                s += vv[fc] * tanhf(acc[fr][fc][i] + dv[fc]);
#pragma unroll
            for (int m = 1; m < 16; m <<= 1) s += __shfl_xor(s, m);
            if ((lane & 15) == 0)
                sEw[wc][(wr << 6) + (fr << 4) + ((lane >> 4) << 2) + i] = s;
        }
    }
    __syncthreads();
    if (tid < 128)
        Epart[(size_t)colb * R_TOTAL + (size_t)rowb * 128 + tid] = sEw[0][tid] + sEw[1][tid];
}

// ======= K2 (fallback, small ws): fused reg-staged fp32->bf16 GEMM =======
__global__ __launch_bounds__(256, 2) void eij_fused_kernel(
        const float* __restrict__ enc, const float* __restrict__ Ua,
        const float* __restrict__ decp, const float* __restrict__ va,
        float* __restrict__ Epart) {
    const int colb = blockIdx.x;
    const int rowb = blockIdx.y;
    const int tid  = threadIdx.x;
    const int lane = tid & 63, wid = tid >> 6;
    const int wr = wid >> 1, wc = wid & 1;
    const int b  = rowb >> 4;

    __shared__ unsigned short sA[128 * 64];
    __shared__ unsigned short sB[128 * 64];
    __shared__ float sEw[2][128];

    const float* Ab = enc + (size_t)rowb * 128 * KDIM;
    const float* Bb = Ua  + (size_t)colb * 128 * KDIM;

    f32x4 acc[4][4];
#pragma unroll
    for (int i = 0; i < 4; ++i)
#pragma unroll
        for (int j = 0; j < 4; ++j) acc[i][j] = (f32x4){0.f, 0.f, 0.f, 0.f};

    for (int k0 = 0; k0 < KDIM; k0 += 64) {
        __syncthreads();
#pragma unroll
        for (int i = 0; i < 8; ++i) {
            int f = tid + (i << 8);
            int row = f >> 4, c = (f & 15) << 2;
            float4 v = *reinterpret_cast<const float4*>(Ab + (size_t)row * KDIM + k0 + c);
            ushort4 hh;
            hh.x = f2bf(v.x); hh.y = f2bf(v.y); hh.z = f2bf(v.z); hh.w = f2bf(v.w);
            int idx = (row * 64 + c) ^ ((row & 7) << 3);
            *reinterpret_cast<ushort4*>(&sA[idx]) = hh;
        }
#pragma unroll
        for (int i = 0; i < 8; ++i) {
            int f = tid + (i << 8);
            int row = f >> 4, c = (f & 15) << 2;
            float4 v = *reinterpret_cast<const float4*>(Bb + (size_t)row * KDIM + k0 + c);
            ushort4 hh;
            hh.x = f2bf(v.x); hh.y = f2bf(v.y); hh.z = f2bf(v.z); hh.w = f2bf(v.w);
            int idx = (row * 64 + c) ^ ((row & 7) << 3);
            *reinterpret_cast<ushort4*>(&sB[idx]) = hh;
        }
        __syncthreads();
#pragma unroll
        for (int kk = 0; kk < 64; kk += 32) {
            const int kb = kk + ((lane >> 4) << 3);
            short8 af[4], bf_[4];
#pragma unroll
            for (int fr = 0; fr < 4; ++fr) {
                int row = (wr << 6) + (fr << 4) + (lane & 15);
                int idx = (row * 64 + kb) ^ ((row & 7) << 3);
                af[fr] = *reinterpret_cast<const short8*>(&sA[idx]);
            }
#pragma unroll
            for (int fc = 0; fc < 4; ++fc) {
                int row = (wc << 6) + (fc << 4) + (lane & 15);
                int idx = (row * 64 + kb) ^ ((row & 7) << 3);
                bf_[fc] = *reinterpret_cast<const short8*>(&sB[idx]);
            }
#pragma unroll
            for (int fr = 0; fr < 4; ++fr)
#pragma unroll
                for (int fc = 0; fc < 4; ++fc)
                    acc[fr][fc] = __builtin_amdgcn_mfma_f32_16x16x32_bf16(
                        af[fr], bf_[fc], acc[fr][fc], 0, 0, 0);
        }
    }

    float dv[4], vv[4];
#pragma unroll
    for (int fc = 0; fc < 4; ++fc) {
        int colg = (colb << 7) + (wc << 6) + (fc << 4) + (lane & 15);
        dv[fc] = decp[(size_t)b * 1024 + colg];
        vv[fc] = va[colg];
    }
#pragma unroll
    for (int fr = 0; fr < 4; ++fr) {
#pragma unroll
        for (int i = 0; i < 4; ++i) {
            float s = 0.f;
#pragma unroll
            for (int fc = 0; fc < 4; ++fc)
                s += vv[fc] * tanhf(acc[fr][fc][i] + dv[fc]);
#pragma unroll
            for (int m = 1; m < 16; m <<= 1) s += __shfl_xor(s, m);
            if ((lane & 15) == 0)
                sEw[wc][(wr << 6) + (fr << 4) + ((lane >> 4) << 2) + i] = s;
        }
    }
    __syncthreads();
    if (tid < 128)
        Epart[(size_t)colb * R_TOTAL + (size_t)rowb * 128 + tid] = sEw[0][tid] + sEw[1][tid];
}

// ---------------- K3: masked softmax over S per batch row ----------------
__global__ void softmax_kernel(const float* __restrict__ Ep,
                               const int* __restrict__ mask,
                               float* __restrict__ alpha) {
    int b = blockIdx.x, tid = threadIdx.x;
    __shared__ float red[4];
    __shared__ float red2[4];
    float ev[8];
#pragma unroll
    for (int j = 0; j < 8; ++j) {
        int s = tid + (j << 8);
        size_t off = (size_t)b * SDIM + s;
        float e = 0.f;
#pragma unroll
        for (int p = 0; p < 8; ++p) e += Ep[(size_t)p * R_TOTAL + off];
        if (mask[off] == 0) e = MASK_FILL;
        ev[j] = e;
    }
    float mx = ev[0];
#pragma unroll
    for (int j = 1; j < 8; ++j) mx = fmaxf(mx, ev[j]);
#pragma unroll
    for (int m = 1; m < 64; m <<= 1) mx = fmaxf(mx, __shfl_xor(mx, m));
    if ((tid & 63) == 0) red[tid >> 6] = mx;
    __syncthreads();
    mx = fmaxf(fmaxf(red[0], red[1]), fmaxf(red[2], red[3]));

    float ex[8], sum = 0.f;
#pragma unroll
    for (int j = 0; j < 8; ++j) { ex[j] = expf(ev[j] - mx); sum += ex[j]; }
#pragma unroll
    for (int m = 1; m < 64; m <<= 1) sum += __shfl_xor(sum, m);
    if ((tid & 63) == 0) red2[tid >> 6] = sum;
    __syncthreads();
    sum = red2[0] + red2[1] + red2[2] + red2[3];
    float inv = 1.0f / sum;
#pragma unroll
    for (int j = 0; j < 8; ++j)
        alpha[(size_t)b * SDIM + tid + (j << 8)] = ex[j] * inv;
}

// ---------------- K4: context partials over s-chunks ----------------
__global__ void ctx_part_kernel(const float* __restrict__ alpha,
                                const float* __restrict__ enc,
                                float* __restrict__ cpart) {
    int ec = blockIdx.x;   // 0..1  (1024 floats each)
    int sc = blockIdx.y;   // 0..7  (256 s each)
    int b  = blockIdx.z;   // 0..63
    int tid = threadIdx.x;
    int e = (ec << 10) + (tid << 2);
    const float* ep = enc + (size_t)b * SDIM * KDIM;
    float4 acc = {0.f, 0.f, 0.f, 0.f};
    int s0 = sc << 8;
#pragma unroll 4
    for (int s = s0; s < s0 + 256; ++s) {
        float a = alpha[(size_t)b * SDIM + s];
        float4 v = *reinterpret_cast<const float4*>(ep + (size_t)s * KDIM + e);
        acc.x += a * v.x; acc.y += a * v.y; acc.z += a * v.z; acc.w += a * v.w;
    }
    *reinterpret_cast<float4*>(cpart + ((size_t)sc * 64 + b) * 2048 + e) = acc;
}

// ---------------- K5: combine context partials ----------------
__global__ void ctx_combine_kernel(const float* __restrict__ cpart,
                                   float* __restrict__ out) {
    int idx = blockIdx.x * 256 + threadIdx.x;   // 0..131071
    float s = 0.f;
#pragma unroll
    for (int y = 0; y < 8; ++y) s += cpart[(size_t)y * 131072 + idx];
    out[idx] = s;
}

extern "C" void kernel_launch(void* const* d_in, const int* in_sizes, int n_in,
                              void* d_out, int out_size, void* d_ws, size_t ws_size,
                              hipStream_t stream) {
    const float* dec  = (const float*)d_in[0];
    const float* enc  = (const float*)d_in[1];
    const int*   mask = (const int*)d_in[2];
    const float* Wa   = (const float*)d_in[3];
    const float* Ua   = (const float*)d_in[4];
    const float* va   = (const float*)d_in[5];

    float* ctx_out   = (float*)d_out;                 // [64][2048]
    float* alpha_out = (float*)d_out + 64 * 2048;     // [64][2048]

    char* ws = (char*)d_ws;
    // layout (bytes):
    //   0        : Epart  8*131072*4   = 4 MiB
    //   4 MiB    : dp     64*1024*4    = 256 KiB
    //   4.25 MiB : cpart  8*131072*4   = 4 MiB
    //   8.25 MiB : Ua16   1024*2048*2  = 4 MiB
    //   12.25 MiB: enc16  131072*2048*2= 512 MiB
    float* Epart = (float*)ws;
    float* dp    = (float*)(ws + (size_t)4 * 1048576);
    float* cpart = (float*)(ws + (size_t)4 * 1048576 + 262144);
    unsigned short* ua16  = (unsigned short*)(ws + (size_t)8 * 1048576 + 262144);
    unsigned short* enc16 = (unsigned short*)(ws + (size_t)12 * 1048576 + 262144);
    const size_t NEED = (size_t)12 * 1048576 + 262144 + (size_t)R_TOTAL * KDIM * 2;

    decproj_kernel<<<16, 256, 0, stream>>>(dec, Wa, dp);

    if (ws_size >= NEED) {
        cvt_bf16_kernel<<<2048, 256, 0, stream>>>(enc, enc16, (size_t)R_TOTAL * KDIM);
        cvt_bf16_kernel<<<1024, 256, 0, stream>>>(Ua, ua16, (size_t)NDIM * KDIM);
        eij_gl_kernel<<<8192, 256, 0, stream>>>(enc16, ua16, dp, va, Epart);
    } else {
        eij_fused_kernel<<<dim3(8, 1024), 256, 0, stream>>>(enc, Ua, dp, va, Epart);
    }

    softmax_kernel<<<64, 256, 0, stream>>>(Epart, mask, alpha_out);
    ctx_part_kernel<<<dim3(2, 8, 64), 256, 0, stream>>>(alpha_out, enc, cpart);
    ctx_combine_kernel<<<512, 256, 0, stream>>>(cpart, ctx_out);
}